// Round 2
// baseline (696.595 us; speedup 1.0000x reference)
//
#include <hip/hip_runtime.h>
#include <stdint.h>
#include <stddef.h>

// Problem constants: B=4, H=16, P=1024, D=128
#define BHC 64
#define PP  1024
#define DD  128
#define BM  64      // q rows per block
#define BN  128     // keys per LDS chunk
#define NCH 8       // P / BN
#define LSTR 136    // LDS row stride in ushorts (272 B -> only 2-way bank aliasing, free per m136)

typedef __bf16 bf16x8 __attribute__((ext_vector_type(8)));
typedef float  f32x4  __attribute__((ext_vector_type(4)));

__device__ __forceinline__ unsigned short f2bf(float x) {
    union { float f; uint32_t u; } v; v.f = x;
    uint32_t r = v.u + 0x7FFFu + ((v.u >> 16) & 1u);   // RNE
    return (unsigned short)(r >> 16);
}

__device__ __forceinline__ float silu_f(float x) {
    return x / (1.0f + __expf(-x));
}

// Fused: silu(q)·silu(k)^T scores via bf16 MFMA, softmax over keys, all in one pass.
// 16 waves = 2 row-groups (wr) x 8 key-groups (wc). acc[8][2] f32x4 = 64 VGPRs/lane
// holds the full 64x1024 score stripe -> single-pass softmax, no score materialization.
// No aF preload (re-read from LDS each chunk) to stay under the 128-VGPR/wave cap
// (16-wave block = 4 waves/SIMD) without spills.
__global__ __launch_bounds__(1024) void attn_fused(
        const float* __restrict__ q, const float* __restrict__ k,
        const float* __restrict__ scale, float* __restrict__ out) {
    __shared__ unsigned short qs [BM * LSTR];   // 17408 B
    __shared__ unsigned short ksm[BN * LSTR];   // 34816 B
    __shared__ float red_m[BM * 8];             // 2048 B
    __shared__ float red_l[BM * 8];             // 2048 B  (total 56320 B < 64 KB)

    // XCD swizzle: consecutive blocks on one XCD sweep qblk first -> the ~32
    // concurrently-resident blocks per XCD share 2 K-tiles (1 MB fp32) in its 4 MiB L2.
    int bx   = blockIdx.x;
    int xcd  = bx & 7;
    int idx  = bx >> 3;               // 0..127
    int bh   = xcd * 8 + (idx >> 4);  // 0..63
    int qblk = idx & 15;

    int t    = threadIdx.x;
    int lane = t & 63;
    int w    = t >> 6;
    int wr   = w & 1;
    int wc   = w >> 1;
    int l15  = lane & 15;
    int quad = lane >> 4;

    const float* qg = q + (size_t)bh * (PP * DD) + (size_t)qblk * (BM * DD);
    const float* kg = k + (size_t)bh * (PP * DD);

    // ---- stage Q tile: 64x128 fp32, silu+cast inline. 2048 float4 units, 2/thread,
    //      unit index = linear -> fully coalesced 16 B/lane contiguous loads. ----
#pragma unroll
    for (int j = 0; j < 2; ++j) {
        int v   = t + j * 1024;
        int row = v >> 5, cu = v & 31;          // 32 float4-units per row
        float4 x = *(const float4*)(qg + row * DD + cu * 4);
        uint2 p;
        p.x = (uint32_t)f2bf(silu_f(x.x)) | ((uint32_t)f2bf(silu_f(x.y)) << 16);
        p.y = (uint32_t)f2bf(silu_f(x.z)) | ((uint32_t)f2bf(silu_f(x.w)) << 16);
        *(uint2*)(&qs[row * LSTR + cu * 4]) = p;
    }

    f32x4 acc[NCH][2];
#pragma unroll
    for (int c = 0; c < NCH; ++c) {
        acc[c][0] = (f32x4)0.0f;
        acc[c][1] = (f32x4)0.0f;
    }

    // ---- K-chunk loop: stage 128x128 fp32 with inline silu+cast, then MFMA ----
#pragma unroll 1
    for (int c = 0; c < NCH; ++c) {
        __syncthreads();   // c=0: guards qs writes; c>0: guards ksm overwrite vs readers
        {
            const float* kc = kg + c * (BN * DD);
#pragma unroll
            for (int j = 0; j < 4; ++j) {       // 4096 float4 units, 4/thread, coalesced
                int v   = t + j * 1024;
                int row = v >> 5, cu = v & 31;
                float4 x = *(const float4*)(kc + row * DD + cu * 4);
                uint2 p;
                p.x = (uint32_t)f2bf(silu_f(x.x)) | ((uint32_t)f2bf(silu_f(x.y)) << 16);
                p.y = (uint32_t)f2bf(silu_f(x.z)) | ((uint32_t)f2bf(silu_f(x.w)) << 16);
                *(uint2*)(&ksm[row * LSTR + cu * 4]) = p;
            }
        }
        __syncthreads();
#pragma unroll
        for (int kk = 0; kk < 4; ++kk) {
            bf16x8 a0 = *(const bf16x8*)(&qs[(wr * 32      + l15) * LSTR + kk * 32 + quad * 8]);
            bf16x8 a1 = *(const bf16x8*)(&qs[(wr * 32 + 16 + l15) * LSTR + kk * 32 + quad * 8]);
            bf16x8 bF = *(const bf16x8*)(&ksm[(wc * 16 + l15) * LSTR + kk * 32 + quad * 8]);
            acc[c][0] = __builtin_amdgcn_mfma_f32_16x16x32_bf16(a0, bF, acc[c][0], 0, 0, 0);
            acc[c][1] = __builtin_amdgcn_mfma_f32_16x16x32_bf16(a1, bF, acc[c][1], 0, 0, 0);
        }
    }

    // ---- softmax over keys (scale folded into exp2 argument) ----
    float C2 = scale[0] * 1.44269504088896340736f;  // scale * log2(e)

    // per-row max: in-lane over chunks, shuffle-xor over 16 cols, LDS across 8 wc groups
#pragma unroll
    for (int rt = 0; rt < 2; ++rt) {
#pragma unroll
        for (int r = 0; r < 4; ++r) {
            float m = acc[0][rt][r];
#pragma unroll
            for (int c = 1; c < NCH; ++c) m = fmaxf(m, acc[c][rt][r]);
#pragma unroll
            for (int off = 1; off < 16; off <<= 1) m = fmaxf(m, __shfl_xor(m, off, 64));
            if (l15 == 0) red_m[(wr * 32 + rt * 16 + quad * 4 + r) * 8 + wc] = m;
        }
    }
    __syncthreads();

#pragma unroll
    for (int rt = 0; rt < 2; ++rt) {
#pragma unroll
        for (int r = 0; r < 4; ++r) {
            int row = wr * 32 + rt * 16 + quad * 4 + r;
            float4 p0 = *(const float4*)(&red_m[row * 8]);
            float4 p1 = *(const float4*)(&red_m[row * 8 + 4]);
            float m = fmaxf(fmaxf(fmaxf(p0.x, p0.y), fmaxf(p0.z, p0.w)),
                            fmaxf(fmaxf(p1.x, p1.y), fmaxf(p1.z, p1.w)));
            float ssum = 0.f;
#pragma unroll
            for (int c = 0; c < NCH; ++c) {
                float e = exp2f((acc[c][rt][r] - m) * C2);
                acc[c][rt][r] = e;
                ssum += e;
            }
#pragma unroll
            for (int off = 1; off < 16; off <<= 1) ssum += __shfl_xor(ssum, off, 64);
            if (l15 == 0) red_l[row * 8 + wc] = ssum;
        }
    }
    __syncthreads();

    float inv[2][4];
#pragma unroll
    for (int rt = 0; rt < 2; ++rt) {
#pragma unroll
        for (int r = 0; r < 4; ++r) {
            int row = wr * 32 + rt * 16 + quad * 4 + r;
            float4 p0 = *(const float4*)(&red_l[row * 8]);
            float4 p1 = *(const float4*)(&red_l[row * 8 + 4]);
            float l = (p0.x + p0.y) + (p0.z + p0.w) + (p1.x + p1.y) + (p1.z + p1.w);
            inv[rt][r] = 1.0f / l;
        }
    }

    // ---- store: lane&15 contiguous keys -> 64 B segments per quarter-wave ----
    float* og = out + ((size_t)bh << 20) + (size_t)(qblk * BM) * PP;
#pragma unroll
    for (int c = 0; c < NCH; ++c) {
#pragma unroll
        for (int rt = 0; rt < 2; ++rt) {
            int key = c * BN + wc * 16 + l15;
            int rb  = wr * 32 + rt * 16 + quad * 4;
#pragma unroll
            for (int r = 0; r < 4; ++r) {
                og[(size_t)(rb + r) * PP + key] = acc[c][rt][r] * inv[rt][r];
            }
        }
    }
}

extern "C" void kernel_launch(void* const* d_in, const int* in_sizes, int n_in,
                              void* d_out, int out_size, void* d_ws, size_t ws_size,
                              hipStream_t stream) {
    const float* q     = (const float*)d_in[0];
    const float* k     = (const float*)d_in[1];
    const float* scale = (const float*)d_in[2];
    float* out = (float*)d_out;
    (void)d_ws; (void)ws_size; (void)in_sizes; (void)n_in; (void)out_size;

    attn_fused<<<1024, 1024, 0, stream>>>(q, k, scale, out);
}